// Round 7
// baseline (784.933 us; speedup 1.0000x reference)
//
#include <hip/hip_runtime.h>
#include <hip/hip_bf16.h>
#include <math.h>

#define HH 56
#define WW 56
#define HWv 3136
#define NROWS 25088          // B*H*W
#define DIMK 1792
#define KP   1920            // padded K stride (60 units of 32; units 56..59 staged-only)
#define CIN 1794
#define COUT 1792
#define MM 3136
#define MROWS 3328           // 13 * 256
#define JT2 13
#define JT1 7
#define NT 98
#define NPH 56               // K unit phases (1792/32)

typedef __bf16 bf16_t;
typedef __bf16 bf16x8 __attribute__((ext_vector_type(8)));
typedef float f32x4 __attribute__((ext_vector_type(4)));

__device__ __forceinline__ void merge3(float& d0, float& d1, float& d2,
                                       float e0, float e1, float e2) {
    bool t0 = d0 <= e0;
    float c0 = t0 ? d0 : e0;
    float x0 = t0 ? d1 : d0, x1 = t0 ? d2 : d1;
    float y0 = t0 ? e0 : e1, y1 = t0 ? e1 : e2;
    bool t1 = x0 <= y0;
    float c1 = t1 ? x0 : y0;
    float c2 = t1 ? fminf(x1, y0) : fminf(x0, y1);
    d0 = c0; d1 = c1; d2 = c2;
}

__device__ __forceinline__ int xcd_swz(int wg, int nwg) {
    int x = wg & 7, idx = wg >> 3;
    int q = nwg >> 3, r = nwg & 7;
    return (x < r ? x * (q + 1) : r * (q + 1) + (x - r) * q) + idx;
}

__device__ __forceinline__ void block_bar() {
    asm volatile("" ::: "memory");
    __builtin_amdgcn_s_barrier();
    asm volatile("" ::: "memory");
}

// ---------------- prep kernels (unchanged, verified R3) ----------------

__global__ __launch_bounds__(256) void k_convw(const float* __restrict__ cw, bf16_t* __restrict__ wb) {
    int idx = blockIdx.x * 256 + threadIdx.x;
    if (idx >= COUT * DIMK) return;
    int o = idx / DIMK, c = idx - o * DIMK;
    wb[(size_t)o * KP + c] = (bf16_t)cw[(size_t)o * CIN + c];
}

__global__ __launch_bounds__(256) void k_bankT(const float* __restrict__ bank, bf16_t* __restrict__ bt) {
    __shared__ float tile[64][65];
    int mt = blockIdx.x * 64;
    int ct = blockIdx.y * 64;
    int l = threadIdx.x & 63;
    int q = threadIdx.x >> 6;
    if (mt < MM) {
        #pragma unroll
        for (int r = 0; r < 16; ++r) {
            int cl = q * 16 + r;
            tile[cl][l] = bank[(size_t)(ct + cl) * MM + mt + l];
        }
        __syncthreads();
        #pragma unroll
        for (int r = 0; r < 16; ++r) {
            int ml = q * 16 + r;
            bt[(size_t)(mt + ml) * KP + ct + l] = (bf16_t)tile[l][ml];
        }
    } else {
        #pragma unroll
        for (int r = 0; r < 16; ++r) {
            int ml = q * 16 + r;
            bt[(size_t)(mt + ml) * KP + ct + l] = (bf16_t)0.f;
        }
    }
}

__global__ __launch_bounds__(256) void k_rowsq(const bf16_t* __restrict__ rows, float* __restrict__ sq) {
    int n = blockIdx.x * 4 + (threadIdx.x >> 6);
    int lane = threadIdx.x & 63;
    const bf16x8* row = (const bf16x8*)(rows + (size_t)n * KP);
    float s = 0.f;
    #pragma unroll
    for (int t = 0; t < 4; ++t) {
        int idx = t * 64 + lane;
        if (idx < 224) {
            bf16x8 v = row[idx];
            #pragma unroll
            for (int j = 0; j < 8; ++j) { float f = (float)v[j]; s += f * f; }
        }
    }
    #pragma unroll
    for (int off = 32; off; off >>= 1) s += __shfl_xor(s, off, 64);
    if (lane == 0) sq[n] = s;
}

__global__ __launch_bounds__(256) void k_pool_s(const float* __restrict__ in, float* __restrict__ out,
                                                int S, int total) {
    int idx = blockIdx.x * 256 + threadIdx.x;
    if (idx >= total) return;
    int x = idx % S; int y = (idx / S) % S; int bc = idx / (S * S);
    const float* base = in + (size_t)bc * S * S;
    float s = 0.f;
    for (int dy = -1; dy <= 1; ++dy) {
        int yy = y + dy; if ((unsigned)yy >= (unsigned)S) continue;
        for (int dx = -1; dx <= 1; ++dx) {
            int xx = x + dx; if ((unsigned)xx >= (unsigned)S) continue;
            s += base[yy * S + xx];
        }
    }
    out[idx] = s * (1.f / 9.f);
}

__global__ __launch_bounds__(256) void k_resize_p(const float* __restrict__ src, bf16_t* __restrict__ dst,
                                                  int S, int total, float scale, float shift) {
    int idx = blockIdx.x * 256 + threadIdx.x;
    if (idx >= total) return;
    int w = idx % WW; int h = (idx / WW) % HH; int bc = idx / HWv;
    float sy = scale * h + shift;
    float sx = scale * w + shift;
    float y0f = floorf(sy), x0f = floorf(sx);
    int y0 = (int)y0f, x0 = (int)x0f;
    float fy = sy - y0f, fx = sx - x0f;
    int iy0 = y0 < 0 ? 0 : (y0 > S - 1 ? S - 1 : y0);
    int iy1 = (y0 + 1) < 0 ? 0 : ((y0 + 1) > S - 1 ? S - 1 : y0 + 1);
    int ix0 = x0 < 0 ? 0 : (x0 > S - 1 ? S - 1 : x0);
    int ix1 = (x0 + 1) < 0 ? 0 : ((x0 + 1) > S - 1 ? S - 1 : x0 + 1);
    const float* base = src + (size_t)bc * S * S;
    float v00 = base[iy0 * S + ix0], v01 = base[iy0 * S + ix1];
    float v10 = base[iy1 * S + ix0], v11 = base[iy1 * S + ix1];
    float v = (1.f - fy) * ((1.f - fx) * v00 + fx * v01) + fy * ((1.f - fx) * v10 + fx * v11);
    dst[idx] = (bf16_t)v;
}

template <typename T>
__global__ __launch_bounds__(256) void k_transp(const T* __restrict__ src, bf16_t* __restrict__ inp,
                                                int Csrc, int coff) {
    __shared__ float tile[64][65];
    int hw0 = blockIdx.x * 64;
    int c0 = blockIdx.y * 64;
    int b = blockIdx.z;
    int l = threadIdx.x & 63;
    int q = threadIdx.x >> 6;
    #pragma unroll
    for (int r = 0; r < 16; ++r) {
        int c = q * 16 + r;
        tile[c][l] = (float)src[(size_t)(b * Csrc + c0 + c) * HWv + hw0 + l];
    }
    __syncthreads();
    #pragma unroll
    for (int r = 0; r < 16; ++r) {
        int ml = q * 16 + r;
        inp[(size_t)(b * HWv + hw0 + ml) * KP + coff + c0 + l] = (bf16_t)tile[l][ml];
    }
}

// ---------------- 256x256 GEMM core: 16x16x32 MFMA, ring-buffer LDS ----------------
// LDS (bf16 elems): A slots 0..4 at s*8192 (16KB each), B slots 0..3 at 40960 + s*8192.
// Unit = [256 rows][32 k]. 16B-granule (r2,S) holds source G = S ^ (r2&7):
// row = 2*r2 + (G>>2), kgranule = G&3 (inverse-swizzled global src, linear LDS dest).
// Phase p: 12 ds_read_b128 -> stage A(p+4),B(p+3) -> 32 MFMA -> vmcnt(8) -> barrier
// (publishes chunk p+1 block-wide before any wave enters phase p+1; vmcnt is per-wave).

__device__ __forceinline__ void gemm256(const bf16_t* __restrict__ A, const bf16_t* __restrict__ Bm,
                                        int n0, int j0, f32x4 (&acc)[8][4], bf16_t* lds) {
    const int tid = threadIdx.x;
    const int lane = tid & 63;
    const int wid = tid >> 6;
    const int wr = wid >> 2;          // 0..1 (M half: 128 rows)
    const int wc = wid & 3;           // 0..3 (N quarter: 64 cols)
    const int lr = lane & 15;
    const int lg = lane >> 4;

    bf16_t* sA = lds;
    bf16_t* sB = lds + 40960;

    #pragma unroll
    for (int m = 0; m < 8; ++m)
        #pragma unroll
        for (int n = 0; n < 4; ++n) acc[m][n] = (f32x4){0.f, 0.f, 0.f, 0.f};

    // ---- staging constants ----
    size_t srcA[2], srcB[2];
    int ldso[2];
    #pragma unroll
    for (int r = 0; r < 2; ++r) {
        int g = r * 512 + tid;          // granule 0..1023
        int r2 = g >> 3, S = g & 7;
        int G = S ^ (r2 & 7);
        int row = 2 * r2 + (G >> 2);
        int kgr = G & 3;
        srcA[r] = (size_t)(n0 + row) * KP + kgr * 8;
        srcB[r] = (size_t)(j0 + row) * KP + kgr * 8;
        ldso[r] = g * 8;
    }
    auto stageA = [&](int slotOff, int kc) {
        #pragma unroll
        for (int r = 0; r < 2; ++r)
            __builtin_amdgcn_global_load_lds(
                (__attribute__((address_space(1))) void*)(A + srcA[r] + kc),
                (__attribute__((address_space(3))) void*)(sA + slotOff + ldso[r]), 16, 0, 0);
    };
    auto stageB = [&](int slotOff, int kc) {
        #pragma unroll
        for (int r = 0; r < 2; ++r)
            __builtin_amdgcn_global_load_lds(
                (__attribute__((address_space(1))) void*)(Bm + srcB[r] + kc),
                (__attribute__((address_space(3))) void*)(sB + slotOff + ldso[r]), 16, 0, 0);
    };

    // ---- fragment read offsets (elems within a unit); m97-verified 16x16x32 maps ----
    int offA[8], offB[4];
    #pragma unroll
    for (int m = 0; m < 8; ++m) {
        int rowU = wr * 128 + m * 16 + lr;
        int r2 = rowU >> 1, par = rowU & 1;
        int G = par * 4 + lg;
        offA[m] = r2 * 64 + (G ^ (r2 & 7)) * 8;
    }
    #pragma unroll
    for (int n = 0; n < 4; ++n) {
        int colU = wc * 64 + n * 16 + lr;
        int r2 = colU >> 1, par = colU & 1;
        int G = par * 4 + lg;
        offB[n] = r2 * 64 + (G ^ (r2 & 7)) * 8;
    }

    // ---- prologue: a0 a1 b0 a2 b1 a3 b2; publish {a0,a1,b0} ----
    stageA(0 * 8192, 0 * 32);
    stageA(1 * 8192, 1 * 32);
    stageB(0 * 8192, 0 * 32);
    stageA(2 * 8192, 2 * 32);
    stageB(1 * 8192, 1 * 32);
    stageA(3 * 8192, 3 * 32);
    stageB(2 * 8192, 2 * 32);
    asm volatile("s_waitcnt vmcnt(8)" ::: "memory");
    block_bar();

    int roA = 0, roB = 0;
    int kcA = 4 * 32, kcB = 3 * 32;

    for (int p = 0; p < NPH; ++p) {
        bf16x8 aF[8], bF[4];
        #pragma unroll
        for (int m = 0; m < 8; ++m)
            aF[m] = *(const bf16x8*)(sA + roA + offA[m]);
        #pragma unroll
        for (int n = 0; n < 4; ++n)
            bF[n] = *(const bf16x8*)(sB + roB + offB[n]);

        int stA = roA - 8192; if (stA < 0) stA = 4 * 8192;
        int stB = roB - 8192; if (stB < 0) stB = 3 * 8192;
        stageA(stA, kcA);
        stageB(stB, kcB);
        kcA += 32; kcB += 32;

        __builtin_amdgcn_s_setprio(1);
        #pragma unroll
        for (int m = 0; m < 8; ++m)
            #pragma unroll
            for (int n = 0; n < 4; ++n)
                acc[m][n] = __builtin_amdgcn_mfma_f32_16x16x32_bf16(
                    aF[m], bF[n], acc[m][n], 0, 0, 0);
        __builtin_amdgcn_s_setprio(0);

        roA += 8192; if (roA == 5 * 8192) roA = 0;
        roB += 8192; if (roB == 4 * 8192) roB = 0;
        asm volatile("s_waitcnt vmcnt(8)" ::: "memory");   // publish chunk p+1
        block_bar();
    }
    asm volatile("s_waitcnt vmcnt(0)" ::: "memory");   // drain own tail stages
}

// C/D map (m89-verified): col = lane&15, row = (lane>>4)*4 + reg

// GEMM1: feats = bf16( inp·wb^T + bias + coord terms )
__global__ __launch_bounds__(512) void k_gemm1(const bf16_t* __restrict__ inp, const bf16_t* __restrict__ wb,
                                               const float* __restrict__ cw, const float* __restrict__ cb,
                                               bf16_t* __restrict__ feats) {
    __shared__ __align__(16) bf16_t lds[73728];
    int wg = xcd_swz(blockIdx.x, NT * JT1);
    int n0 = (wg / JT1) * 256, j0 = (wg % JT1) * 256;
    f32x4 acc[8][4];
    gemm256(inp, wb, n0, j0, acc, lds);

    const int lane = threadIdx.x & 63, wid = threadIdx.x >> 6;
    const int wr = wid >> 2, wc = wid & 3, lr = lane & 15, lg = lane >> 4;
    float w1[4], w2[4], bb[4];
    int oc[4];
    #pragma unroll
    for (int n = 0; n < 4; ++n) {
        int o = j0 + wc * 64 + n * 16 + lr;
        oc[n] = o;
        bb[n] = cb[o];
        w1[n] = cw[(size_t)o * CIN + DIMK];
        w2[n] = cw[(size_t)o * CIN + DIMK + 1];
    }
    #pragma unroll
    for (int m = 0; m < 8; ++m) {
        #pragma unroll
        for (int v = 0; v < 4; ++v) {
            int nrow = n0 + wr * 128 + m * 16 + lg * 4 + v;
            int hw = nrow % HWv;
            int h = hw / WW, w = hw - h * WW;
            float xx = (2.f / 55.f) * w - 1.f;
            float yy = (2.f / 55.f) * h - 1.f;
            #pragma unroll
            for (int n = 0; n < 4; ++n) {
                float phi = acc[m][n][v] + bb[n] + xx * w1[n] + yy * w2[n];
                feats[(size_t)nrow * KP + oc[n]] = (bf16_t)phi;
            }
        }
    }
}

// GEMM2 + per-row top3 of s = csq[m] - 2*dot within this 256-col j-tile.
// Per-wave in-register merge covers only this wave's 64-col quarter; the four
// wc-waves' triples are combined via an LDS table [256 rows][4 wc][3] (this was
// the R4/R5 bug: all 4 wc-waves raced on one partial slot -> top3 of 1/4 of cols).
__global__ __launch_bounds__(512) void k_gemm2(const bf16_t* __restrict__ feats, const bf16_t* __restrict__ bt,
                                               const float* __restrict__ csq, float* __restrict__ partial) {
    __shared__ __align__(16) bf16_t lds[73728];
    int wg = xcd_swz(blockIdx.x, NT * JT2);
    int nt = wg / JT2, jt = wg % JT2;
    int n0 = nt * 256, j0 = jt * 256;
    f32x4 acc[8][4];
    gemm256(feats, bt, n0, j0, acc, lds);

    // every wave has done vmcnt(0): one barrier makes ALL tail DMA writes visible
    // and LDS safely recyclable for the reduction table.
    block_bar();

    const int tid = threadIdx.x;
    const int lane = tid & 63, wid = tid >> 6;
    const int wr = wid >> 2, wc = wid & 3, lr = lane & 15, lg = lane >> 4;
    const float BIG = 3.0e38f;

    float csqv[4];
    bool mval[4];
    #pragma unroll
    for (int n = 0; n < 4; ++n) {
        int m = j0 + wc * 64 + n * 16 + lr;
        mval[n] = (m < MM);
        csqv[n] = mval[n] ? csq[m] : 0.f;
    }

    float* lf = (float*)lds;   // [256][4][3]

    #pragma unroll
    for (int m = 0; m < 8; ++m) {
        #pragma unroll
        for (int v = 0; v < 4; ++v) {
            float a0 = mval[0] ? csqv[0] - 2.f * acc[m][0][v] : BIG;
            float a1 = mval[1] ? csqv[1] - 2.f * acc[m][1][v] : BIG;
            float a2 = mval[2] ? csqv[2] - 2.f * acc[m][2][v] : BIG;
            float a3 = mval[3] ? csqv[3] - 2.f * acc[m][3][v] : BIG;
            float t;
            if (a0 > a1) { t = a0; a0 = a1; a1 = t; }
            if (a2 > a3) { t = a2; a2 = a3; a3 = t; }
            if (a0 > a2) { t = a0; a0 = a2; a2 = t; }
            if (a1 > a3) { t = a1; a1 = a3; a3 = t; }
            if (a1 > a2) { t = a1; a1 = a2; a2 = t; }
            float d0 = a0, d1 = a1, d2 = a2;
            #pragma unroll
            for (int off = 1; off < 16; off <<= 1) {
                float e0 = __shfl_xor(d0, off, 64);
                float e1 = __shfl_xor(d1, off, 64);
                float e2 = __shfl_xor(d2, off, 64);
                merge3(d0, d1, d2, e0, e1, e2);
            }
            if (lr == 0) {
                int rowl = wr * 128 + m * 16 + lg * 4 + v;   // 0..255
                int bix = (rowl * 4 + wc) * 3;
                lf[bix] = d0; lf[bix + 1] = d1; lf[bix + 2] = d2;
            }
        }
    }
    __syncthreads();
    if (tid < 256) {
        int base = tid * 12;
        float d0 = lf[base], d1 = lf[base + 1], d2 = lf[base + 2];
        #pragma unroll
        for (int q = 1; q < 4; ++q)
            merge3(d0, d1, d2, lf[base + q * 3], lf[base + q * 3 + 1], lf[base + q * 3 + 2]);
        float* pp = partial + (size_t)(n0 + tid) * (JT2 * 3) + jt * 3;
        pp[0] = d0; pp[1] = d1; pp[2] = d2;
    }
}

__global__ __launch_bounds__(256) void k_score(const float* __restrict__ partial, const float* __restrict__ fsq,
                                               float* __restrict__ out) {
    int row = blockIdx.x * 256 + threadIdx.x;
    if (row >= NROWS) return;
    const float* p = partial + (size_t)row * (JT2 * 3);
    float d0 = p[0], d1 = p[1], d2 = p[2];
    #pragma unroll
    for (int jt = 1; jt < JT2; ++jt)
        merge3(d0, d1, d2, p[jt * 3], p[jt * 3 + 1], p[jt * 3 + 2]);
    float fs = fsq[row];
    d0 = sqrtf(fmaxf(fs + d0, 0.f));
    d1 = sqrtf(fmaxf(fs + d1, 0.f));
    d2 = sqrtf(fmaxf(fs + d2, 0.f));
    float e1 = expf(d0 - d1), e2 = expf(d0 - d2);
    out[row] = d0 / (1.f + e1 + e2);
}

// ---------------- launch ----------------

extern "C" void kernel_launch(void* const* d_in, const int* in_sizes, int n_in,
                              void* d_out, int out_size, void* d_ws, size_t ws_size,
                              hipStream_t stream) {
    const float* f1   = (const float*)d_in[0];
    const float* f2   = (const float*)d_in[1];
    const float* f3   = (const float*)d_in[2];
    const float* cw   = (const float*)d_in[3];
    const float* cb   = (const float*)d_in[4];
    const float* bank = (const float*)d_in[5];
    float* out = (float*)d_out;
    char* ws = (char*)d_ws;

    size_t off = 0;
    auto alloc = [&](size_t bytes) { size_t o = off; off = (off + bytes + 255) & ~(size_t)255; return o; };
    bf16_t* wb      = (bf16_t*)(ws + alloc((size_t)COUT * KP * 2));
    bf16_t* bt      = (bf16_t*)(ws + alloc((size_t)MROWS * KP * 2));
    float*  fsq     = (float*)(ws + alloc((size_t)NROWS * 4));
    float*  csq     = (float*)(ws + alloc((size_t)MM * 4));
    float*  partial = (float*)(ws + alloc((size_t)NROWS * JT2 * 3 * 4));
    bf16_t* inp     = (bf16_t*)(ws + alloc((size_t)NROWS * KP * 2));
    bf16_t* feats   = (bf16_t*)(ws + alloc((size_t)NROWS * KP * 2));

    // prep scratch aliased inside (currently dead) feats region
    char* fb = (char*)feats;
    float*  p1  = (float*)fb;
    float*  p2s = (float*)(fb + 25690112);
    bf16_t* r2b = (bf16_t*)(fb + 25690112 + 12845056);
    float*  p3s = (float*)fb;
    bf16_t* r3b = (bf16_t*)(fb + 6422528);

    k_convw<<<dim3((COUT * DIMK + 255) / 256), dim3(256), 0, stream>>>(cw, wb);
    k_bankT<<<dim3(MROWS / 64, DIMK / 64), dim3(256), 0, stream>>>(bank, bt);
    k_rowsq<<<dim3(MM / 4), dim3(256), 0, stream>>>(bt, csq);

    k_pool_s<<<dim3((8 * 256 * HWv + 255) / 256), dim3(256), 0, stream>>>(f1, p1, 56, 8 * 256 * HWv);
    k_pool_s<<<dim3((8 * 512 * 784 + 255) / 256), dim3(256), 0, stream>>>(f2, p2s, 28, 8 * 512 * 784);
    k_resize_p<<<dim3((8 * 512 * HWv + 255) / 256), dim3(256), 0, stream>>>(p2s, r2b, 28, 8 * 512 * HWv, 0.5f, -0.25f);
    k_transp<float><<<dim3(HWv / 64, 256 / 64, 8), dim3(256), 0, stream>>>(p1, inp, 256, 0);
    k_transp<bf16_t><<<dim3(HWv / 64, 512 / 64, 8), dim3(256), 0, stream>>>(r2b, inp, 512, 256);
    k_pool_s<<<dim3((8 * 1024 * 196 + 255) / 256), dim3(256), 0, stream>>>(f3, p3s, 14, 8 * 1024 * 196);
    k_resize_p<<<dim3((8 * 1024 * HWv + 255) / 256), dim3(256), 0, stream>>>(p3s, r3b, 14, 8 * 1024 * HWv, 0.25f, -0.375f);
    k_transp<bf16_t><<<dim3(HWv / 64, 1024 / 64, 8), dim3(256), 0, stream>>>(r3b, inp, 1024, 768);

    k_gemm1<<<dim3(NT * JT1), dim3(512), 0, stream>>>(inp, wb, cw, cb, feats);
    k_rowsq<<<dim3(NROWS / 4), dim3(256), 0, stream>>>(feats, fsq);
    k_gemm2<<<dim3(NT * JT2), dim3(512), 0, stream>>>(feats, bt, csq, partial);
    k_score<<<dim3((NROWS + 255) / 256), dim3(256), 0, stream>>>(partial, fsq, out);
}